// Round 9
// baseline (443.470 us; speedup 1.0000x reference)
//
#include <hip/hip_runtime.h>

#define NF 64
#define BUCKET 128          // nodes per bucket (dstlocal = 7 bits)
#define MAXB 8192           // max buckets supported by LDS hist
#define EPB 4096            // edges per block in bhist
#define SEPB 16384          // edges per block in bscatter (loop 2-pass)

typedef __attribute__((ext_vector_type(8))) short bf16x8;
typedef __attribute__((ext_vector_type(4))) float f32x4;
typedef __attribute__((ext_vector_type(4))) unsigned int u32x4;

__device__ __forceinline__ float bf2f(unsigned short x) {
    union { unsigned int u; float f; } v; v.u = ((unsigned int)x) << 16; return v.f;
}
__device__ __forceinline__ unsigned short f2bf(float x) {
    union { float f; unsigned int u; } v; v.f = x;
    unsigned int r = (v.u + 0x7FFFu + ((v.u >> 16) & 1u)) >> 16;
    return (unsigned short)r;
}

// =================== bucket build ===================

__global__ __launch_bounds__(256) void bhist_kernel(const int* __restrict__ dst,
                                                    int* __restrict__ bins,
                                                    int n_edges, int nb) {
    __shared__ int h[MAXB];
    for (int i = threadIdx.x; i < nb; i += 256) h[i] = 0;
    __syncthreads();
    int base = blockIdx.x * EPB;
    int lim = min(base + EPB, n_edges);
    for (int i = base + threadIdx.x; i < lim; i += 256)
        atomicAdd(&h[dst[i] >> 7], 1);
    __syncthreads();
    for (int i = threadIdx.x; i < nb; i += 256) {
        int v = h[i];
        if (v) atomicAdd(&bins[i], v);
    }
}

__global__ __launch_bounds__(1024) void bscan_kernel(const int* __restrict__ bins,
                                                     int* __restrict__ bptr,
                                                     int* __restrict__ gcur, int nb) {
    __shared__ int sd[1024];
    int carry = 0;
    if (threadIdx.x == 0) bptr[0] = 0;
    for (int base = 0; base < nb; base += 1024) {
        int i = base + threadIdx.x;
        int v = (i < nb) ? bins[i] : 0;
        sd[threadIdx.x] = v;
        __syncthreads();
        for (int off = 1; off < 1024; off <<= 1) {
            int t = (threadIdx.x >= off) ? sd[threadIdx.x - off] : 0;
            __syncthreads();
            sd[threadIdx.x] += t;
            __syncthreads();
        }
        if (i < nb) {
            bptr[i + 1] = carry + sd[threadIdx.x];
            gcur[i] = carry + sd[threadIdx.x] - v;
        }
        int last = sd[1023];
        __syncthreads();
        carry += last;
    }
}

// two-pass counting scatter over SEPB-edge chunks; packed (src<<7)|(dst&127)
__global__ __launch_bounds__(256) void bscatter_kernel(const int* __restrict__ src,
                                                       const int* __restrict__ dst,
                                                       int* __restrict__ gcur,
                                                       unsigned* __restrict__ bedges,
                                                       int n_edges, int nb) {
    __shared__ int h[MAXB];
    for (int i = threadIdx.x; i < nb; i += 256) h[i] = 0;
    __syncthreads();
    int base = blockIdx.x * SEPB;
    int lim = min(base + SEPB, n_edges);
    for (int i = base + threadIdx.x; i < lim; i += 256)
        atomicAdd(&h[dst[i] >> 7], 1);
    __syncthreads();
    for (int i = threadIdx.x; i < nb; i += 256) {
        int v = h[i];
        h[i] = v ? atomicAdd(&gcur[i], v) : 0;
    }
    __syncthreads();
    for (int i = base + threadIdx.x; i < lim; i += 256) {
        int d = dst[i];
        int pos = atomicAdd(&h[d >> 7], 1);
        bedges[pos] = ((unsigned)src[i] << 7) | (unsigned)(d & 127);
    }
}

__global__ __launch_bounds__(256) void bfinal_kernel(
    const unsigned* __restrict__ bedges, const int* __restrict__ bptr,
    int* __restrict__ row_ptr, int* __restrict__ col,
    int n_nodes, int n_edges, int nb) {
    __shared__ int cnt[BUCKET];
    __shared__ int sa[BUCKET], sb2[BUCKET];
    int tid = threadIdx.x;
    int b = blockIdx.x;
    int beg = bptr[b], end = bptr[b + 1];
    if (tid < BUCKET) cnt[tid] = 0;
    __syncthreads();
    for (int i = beg + tid; i < end; i += 256)
        atomicAdd(&cnt[bedges[i] & (BUCKET - 1)], 1);
    __syncthreads();
    if (tid < BUCKET) sa[tid] = cnt[tid];
    __syncthreads();
    int* pin = sa; int* pout = sb2;
    for (int off = 1; off < BUCKET; off <<= 1) {
        if (tid < BUCKET) pout[tid] = pin[tid] + ((tid >= off) ? pin[tid - off] : 0);
        __syncthreads();
        int* t = pin; pin = pout; pout = t;
    }
    int nodeBase = b * BUCKET;
    if (tid < BUCKET && nodeBase + tid < n_nodes)
        row_ptr[nodeBase + tid] = beg + (tid ? pin[tid - 1] : 0);
    if (b == nb - 1 && tid == 0) row_ptr[n_nodes] = n_edges;
    __syncthreads();
    if (tid < BUCKET) cnt[tid] = 0;
    __syncthreads();
    for (int i = beg + tid; i < end; i += 256) {
        unsigned e = bedges[i];
        int d = e & (BUCKET - 1);
        int pos = beg + (d ? pin[d - 1] : 0) + atomicAdd(&cnt[d], 1);
        col[pos] = (int)(e >> 7);
    }
}

// =================== staging (plane layout) ===================
// XP[p][n][8] bf16, p=0..7: features 8p..8p+8 of node n. Plane = 1.6 MB.

__global__ void convert_kernel(const float* __restrict__ in, unsigned short* __restrict__ XP, int n_nodes) {
    int t = blockIdx.x * blockDim.x + threadIdx.x;
    int total = n_nodes * 16;
    if (t >= total) return;
    int n = t >> 4, g = t & 15;                 // g = feature quad
    float4 v = *reinterpret_cast<const float4*>(in + (size_t)n * 64 + g * 4);
    ushort4 o;
    o.x = f2bf(v.x); o.y = f2bf(v.y); o.z = f2bf(v.z); o.w = f2bf(v.w);
    int p = g >> 1, off = (g & 1) * 4;
    *reinterpret_cast<ushort4*>(XP + ((size_t)p * n_nodes + n) * 8 + off) = o;
}

// all 3 layers' weights -> WT[layer][j][k], k<64 self, k>=64 neigh
__global__ void wtrans_kernel(const float* __restrict__ Ws0, const float* __restrict__ Wn0,
                              const float* __restrict__ Ws1, const float* __restrict__ Wn1,
                              const float* __restrict__ Ws2, const float* __restrict__ Wn2,
                              unsigned short* __restrict__ WT) {
    int t = blockIdx.x * blockDim.x + threadIdx.x;
    if (t >= 3 * 64 * 128) return;
    int layer = t >> 13;
    int r = t & 8191;
    int j = r >> 7, k = r & 127;
    const float* Ws = layer == 0 ? Ws0 : (layer == 1 ? Ws1 : Ws2);
    const float* Wn = layer == 0 ? Wn0 : (layer == 1 ? Wn1 : Wn2);
    float v = (k < 64) ? Ws[k * 64 + j] : Wn[(k - 64) * 64 + j];
    WT[t] = f2bf(v);
}

// =================== aggregation: feature-sliced, XCD-pinned ===================
// slice s = blockIdx%8 -> XCD s (round-robin heuristic): per-XCD working set =
// one 1.6MB plane -> L2-resident. Block: 4 waves x 4 nodes; 16 lanes per node
// (slot = edge index mod 16); each lane loads 16 B (8 feats) of one edge.
__global__ __launch_bounds__(256) void aggregate_sliced_kernel(
    const unsigned short* __restrict__ XP,   // h planes [8][N][8]
    unsigned short* __restrict__ AP,         // agg planes [8][N][8]
    const int* __restrict__ row_ptr, const int* __restrict__ col,
    int n_nodes) {
    int s = blockIdx.x & 7;
    int group = blockIdx.x >> 3;
    int tid = threadIdx.x;
    int wid = tid >> 6;
    int lane = tid & 63;
    int sub = lane >> 4;      // node within wave (0..3)
    int slot = lane & 15;     // edge slot
    int n = group * 16 + wid * 4 + sub;
    if (n >= n_nodes) return;
    int beg = row_ptr[n], end = row_ptr[n + 1];
    const unsigned short* plane = XP + (size_t)s * n_nodes * 8;

    float a[8] = {0.f, 0.f, 0.f, 0.f, 0.f, 0.f, 0.f, 0.f};
    for (int i = beg + slot; i < end; i += 16) {
        int sidx = __builtin_nontemporal_load(col + i);
        u32x4 v = *reinterpret_cast<const u32x4*>(plane + (size_t)sidx * 8);
#pragma unroll
        for (int k = 0; k < 4; ++k) {
            union { unsigned u; float f; } lo, hi;
            lo.u = v[k] << 16; hi.u = v[k] & 0xffff0000u;
            a[2 * k] += lo.f; a[2 * k + 1] += hi.f;
        }
    }
#pragma unroll
    for (int k = 0; k < 8; ++k) {
        a[k] += __shfl_xor(a[k], 1);
        a[k] += __shfl_xor(a[k], 2);
        a[k] += __shfl_xor(a[k], 4);
        a[k] += __shfl_xor(a[k], 8);
    }
    if (slot == 0) {
        float dinv = 1.0f / fmaxf((float)(end - beg), 1.0f);
        u32x4 o;
#pragma unroll
        for (int k = 0; k < 4; ++k)
            o[k] = ((unsigned)f2bf(a[2 * k + 1] * dinv) << 16) | f2bf(a[2 * k] * dinv);
        *reinterpret_cast<u32x4*>(AP + ((size_t)s * n_nodes + n) * 8) = o;
    }
}

// =================== MFMA linear (plane-layout inputs) ===================
// OUT[node][feat] = [relu]( [h | agg] @ WT^T + b ).
// B-frag xf[ks]: k = ks*32 + lg*8 + e  ->  h plane 4ks+lg (ks<2),
// agg plane 4(ks-2)+lg (ks>=2), 16B contiguous per lane.
__global__ __launch_bounds__(256) void linear_mfma_kernel(
    const unsigned short* __restrict__ XP,   // h planes
    const unsigned short* __restrict__ AP,   // agg planes
    const unsigned short* __restrict__ WT,
    const float* __restrict__ bias,
    unsigned short* __restrict__ XPout,      // bf16 planes out, or null
    float* __restrict__ outF32,              // f32 [N][64] out, or null
    int n_nodes, int do_relu) {
    int lane = threadIdx.x & 63;
    int wid = threadIdx.x >> 6;
    int l15 = lane & 15;
    int lg = lane >> 4;

    bf16x8 wf[4][4];
#pragma unroll
    for (int ft = 0; ft < 4; ++ft)
#pragma unroll
        for (int ks = 0; ks < 4; ++ks)
            wf[ft][ks] = *reinterpret_cast<const bf16x8*>(
                WT + (size_t)(ft * 16 + l15) * 128 + ks * 32 + lg * 8);

    float4 bv[4];
#pragma unroll
    for (int ft = 0; ft < 4; ++ft)
        bv[ft] = *reinterpret_cast<const float4*>(bias + ft * 16 + lg * 4);

    int tiles = (n_nodes + 15) >> 4;
    for (int tile = blockIdx.x * 4 + wid; tile < tiles; tile += gridDim.x * 4) {
        int nodeBase = tile * 16;
        int nrow = nodeBase + l15;
        int rrow = nrow < n_nodes ? nrow : n_nodes - 1;

        bf16x8 xf[4];
        xf[0] = *reinterpret_cast<const bf16x8*>(XP + ((size_t)(lg)     * n_nodes + rrow) * 8);
        xf[1] = *reinterpret_cast<const bf16x8*>(XP + ((size_t)(4 + lg) * n_nodes + rrow) * 8);
        xf[2] = *reinterpret_cast<const bf16x8*>(AP + ((size_t)(lg)     * n_nodes + rrow) * 8);
        xf[3] = *reinterpret_cast<const bf16x8*>(AP + ((size_t)(4 + lg) * n_nodes + rrow) * 8);

        f32x4 acc[4];
#pragma unroll
        for (int ft = 0; ft < 4; ++ft) acc[ft] = (f32x4){0.f, 0.f, 0.f, 0.f};
#pragma unroll
        for (int ks = 0; ks < 4; ++ks) {
#pragma unroll
            for (int ft = 0; ft < 4; ++ft)
                acc[ft] = __builtin_amdgcn_mfma_f32_16x16x32_bf16(wf[ft][ks], xf[ks], acc[ft], 0, 0, 0);
        }

        if (nrow < n_nodes) {
#pragma unroll
            for (int ft = 0; ft < 4; ++ft) {
                float4 v;
                v.x = acc[ft][0] + bv[ft].x;
                v.y = acc[ft][1] + bv[ft].y;
                v.z = acc[ft][2] + bv[ft].z;
                v.w = acc[ft][3] + bv[ft].w;
                if (do_relu) {
                    v.x = fmaxf(v.x, 0.f); v.y = fmaxf(v.y, 0.f);
                    v.z = fmaxf(v.z, 0.f); v.w = fmaxf(v.w, 0.f);
                }
                int fbase = ft * 16 + lg * 4;
                if (outF32) {
                    *reinterpret_cast<float4*>(outF32 + (size_t)nrow * 64 + fbase) = v;
                } else {
                    ushort4 o;
                    o.x = f2bf(v.x); o.y = f2bf(v.y); o.z = f2bf(v.z); o.w = f2bf(v.w);
                    int p = 2 * ft + (lg >> 1), off = (lg & 1) * 4;
                    *reinterpret_cast<ushort4*>(XPout + ((size_t)p * n_nodes + nrow) * 8 + off) = o;
                }
            }
        }
    }
}

// =================== fallback (round-1 atomic scatter, f32) ===================

__global__ void deg_kernel(const int* __restrict__ dst, float* __restrict__ deg, int n_edges) {
    int e = blockIdx.x * blockDim.x + threadIdx.x;
    if (e < n_edges) unsafeAtomicAdd(&deg[dst[e]], 1.0f);
}

__global__ void inv_kernel(float* __restrict__ deg, int n) {
    int i = blockIdx.x * blockDim.x + threadIdx.x;
    if (i < n) deg[i] = 1.0f / fmaxf(deg[i], 1.0f);
}

__global__ __launch_bounds__(256) void scatter_kernel(
    const float* __restrict__ h, const int* __restrict__ src, const int* __restrict__ dst,
    float* __restrict__ agg, int n_edges) {
    int t = blockIdx.x * blockDim.x + threadIdx.x;
    int e = t >> 4;
    if (e >= n_edges) return;
    int q = (t & 15) * 4;
    int s = src[e];
    int d = dst[e];
    float4 v = *reinterpret_cast<const float4*>(h + (size_t)s * NF + q);
    float* o = agg + (size_t)d * NF + q;
    unsafeAtomicAdd(o + 0, v.x);
    unsafeAtomicAdd(o + 1, v.y);
    unsafeAtomicAdd(o + 2, v.z);
    unsafeAtomicAdd(o + 3, v.w);
}

__global__ __launch_bounds__(256) void linear_kernel(
    const float* __restrict__ h, const float* __restrict__ agg, const float* __restrict__ deginv,
    const float* __restrict__ Ws, const float* __restrict__ Wn, const float* __restrict__ bias,
    float* __restrict__ out, int n_nodes, int do_relu) {
    __shared__ float sWs[NF * NF];
    __shared__ float sWn[NF * NF];
    __shared__ float sb[NF];
    for (int i = threadIdx.x; i < NF * NF; i += 256) {
        sWs[i] = Ws[i];
        sWn[i] = Wn[i];
    }
    if (threadIdx.x < NF) sb[threadIdx.x] = bias[threadIdx.x];
    __syncthreads();
    int j = threadIdx.x & 63;
    int sub = threadIdx.x >> 6;
    for (int n = blockIdx.x * 4 + sub; n < n_nodes; n += gridDim.x * 4) {
        const float4* hr = reinterpret_cast<const float4*>(h + (size_t)n * NF);
        const float4* ar = reinterpret_cast<const float4*>(agg + (size_t)n * NF);
        float accS = 0.f, accN = 0.f;
#pragma unroll
        for (int k4 = 0; k4 < 16; ++k4) {
            float4 hv = hr[k4];
            float4 av = ar[k4];
            int kb = k4 * 4;
            accS += hv.x * sWs[(kb + 0) * NF + j];
            accN += av.x * sWn[(kb + 0) * NF + j];
            accS += hv.y * sWs[(kb + 1) * NF + j];
            accN += av.y * sWn[(kb + 1) * NF + j];
            accS += hv.z * sWs[(kb + 2) * NF + j];
            accN += av.z * sWn[(kb + 2) * NF + j];
            accS += hv.w * sWs[(kb + 3) * NF + j];
            accN += av.w * sWn[(kb + 3) * NF + j];
        }
        float val = accS + deginv[n] * accN + sb[j];
        if (do_relu) val = fmaxf(val, 0.f);
        out[(size_t)n * NF + j] = val;
    }
}

// =================== launch ===================

extern "C" void kernel_launch(void* const* d_in, const int* in_sizes, int n_in,
                              void* d_out, int out_size, void* d_ws, size_t ws_size,
                              hipStream_t stream) {
    const float* features = (const float*)d_in[0];
    const int* src = (const int*)d_in[1];
    const int* dst = (const int*)d_in[2];
    const float* Ws0 = (const float*)d_in[3];
    const float* Wn0 = (const float*)d_in[4];
    const float* b0  = (const float*)d_in[5];
    const float* Ws1 = (const float*)d_in[6];
    const float* Wn1 = (const float*)d_in[7];
    const float* b1  = (const float*)d_in[8];
    const float* Ws2 = (const float*)d_in[9];
    const float* Wn2 = (const float*)d_in[10];
    const float* b2  = (const float*)d_in[11];

    const int n_nodes = in_sizes[0] / NF;
    const int n_edges = in_sizes[1];
    float* out = (float*)d_out;

    const int nb = (n_nodes + BUCKET - 1) / BUCKET;
    const size_t alignNB = (((size_t)nb + 1) * 4 + 255) / 256 * 256;
    const size_t alignN = (((size_t)n_nodes + 64) * 4 + 255) / 256 * 256;
    const size_t alignE = ((size_t)n_edges * 4 + 255) / 256 * 256;
    const size_t xBytes = ((size_t)n_nodes * 64 * 2 + 255) / 256 * 256;  // 8 planes x N x 8 bf16
    const size_t wtBytes = 3 * 64 * 128 * 2;

    dim3 blk(256);
    const int nEB = (n_edges + EPB - 1) / EPB;
    const int nSB = (n_edges + SEPB - 1) / SEPB;
    const int tiles = (n_nodes + 15) / 16;
    const int linBlocks = (tiles + 3) / 4;
    const int aggBlocks = 8 * ((n_nodes + 15) / 16);

    // ws layout: bins | bptr | gcur | row_ptr | col | XP0 | XP1 | AP | WTall
    const size_t need = 3 * alignNB + alignN + alignE + 3 * xBytes + wtBytes;
    const bool outFits = (size_t)out_size * sizeof(float) >= (size_t)n_edges * sizeof(unsigned);

    if (ws_size >= need && nb <= MAXB && n_nodes < (1 << 25) && outFits) {
        char* ws = (char*)d_ws;
        int* bins     = (int*)ws;
        int* bptr     = (int*)(ws + alignNB);
        int* gcur     = (int*)(ws + 2 * alignNB);
        int* row_ptr  = (int*)(ws + 3 * alignNB);
        int* col      = (int*)(ws + 3 * alignNB + alignN);
        unsigned short* XP0 = (unsigned short*)(ws + 3 * alignNB + alignN + alignE);
        unsigned short* XP1 = (unsigned short*)((char*)XP0 + xBytes);
        unsigned short* AP  = (unsigned short*)((char*)XP1 + xBytes);
        unsigned short* WT  = (unsigned short*)((char*)AP + xBytes);
        unsigned short* WT0 = WT;
        unsigned short* WT1 = WT + 64 * 128;
        unsigned short* WT2 = WT + 2 * 64 * 128;
        unsigned* bedges = (unsigned*)d_out;   // dead before final linear writes d_out

        // bucket build
        hipMemsetAsync(bins, 0, (size_t)nb * sizeof(int), stream);
        bhist_kernel<<<nEB, blk, 0, stream>>>(dst, bins, n_edges, nb);
        bscan_kernel<<<1, 1024, 0, stream>>>(bins, bptr, gcur, nb);
        bscatter_kernel<<<nSB, blk, 0, stream>>>(src, dst, gcur, bedges, n_edges, nb);
        bfinal_kernel<<<nb, blk, 0, stream>>>(bedges, bptr, row_ptr, col, n_nodes, n_edges, nb);

        // staging
        convert_kernel<<<(n_nodes * 16 + 255) / 256, blk, 0, stream>>>(features, XP0, n_nodes);
        wtrans_kernel<<<96, blk, 0, stream>>>(Ws0, Wn0, Ws1, Wn1, Ws2, Wn2, WT);

        // layer 0: XP0 -> XP1
        aggregate_sliced_kernel<<<aggBlocks, blk, 0, stream>>>(XP0, AP, row_ptr, col, n_nodes);
        linear_mfma_kernel<<<linBlocks, blk, 0, stream>>>(XP0, AP, WT0, b0, XP1, nullptr, n_nodes, 1);
        // layer 1: XP1 -> XP0
        aggregate_sliced_kernel<<<aggBlocks, blk, 0, stream>>>(XP1, AP, row_ptr, col, n_nodes);
        linear_mfma_kernel<<<linBlocks, blk, 0, stream>>>(XP1, AP, WT1, b1, XP0, nullptr, n_nodes, 1);
        // layer 2: XP0 -> d_out (f32)
        aggregate_sliced_kernel<<<aggBlocks, blk, 0, stream>>>(XP0, AP, row_ptr, col, n_nodes);
        linear_mfma_kernel<<<linBlocks, blk, 0, stream>>>(XP0, AP, WT2, b2, nullptr, out, n_nodes, 0);
    } else {
        // fallback: atomic-scatter path (f32)
        char* ws = (char*)d_ws;
        size_t degBytes = (((size_t)n_nodes * 4) + 255) / 256 * 256;
        float* deg = (float*)ws;
        float* agg = (float*)(ws + degBytes);
        float* h1  = agg + (size_t)n_nodes * NF;
        int scatBlocks = (n_edges * 16 + 255) / 256;
        int eBlocks = (n_edges + 255) / 256;
        int waveBlocks = (n_nodes + 3) / 4;
        size_t rowBytes = (size_t)n_nodes * NF * sizeof(float);

        hipMemsetAsync(deg, 0, (size_t)n_nodes * sizeof(float), stream);
        deg_kernel<<<eBlocks, blk, 0, stream>>>(dst, deg, n_edges);
        inv_kernel<<<(n_nodes + 255) / 256, blk, 0, stream>>>(deg, n_nodes);

        hipMemsetAsync(agg, 0, rowBytes, stream);
        scatter_kernel<<<scatBlocks, blk, 0, stream>>>(features, src, dst, agg, n_edges);
        linear_kernel<<<waveBlocks, blk, 0, stream>>>(features, agg, deg, Ws0, Wn0, b0, out, n_nodes, 1);

        hipMemsetAsync(agg, 0, rowBytes, stream);
        scatter_kernel<<<scatBlocks, blk, 0, stream>>>(out, src, dst, agg, n_edges);
        linear_kernel<<<waveBlocks, blk, 0, stream>>>(out, agg, deg, Ws1, Wn1, b1, h1, n_nodes, 1);

        hipMemsetAsync(agg, 0, rowBytes, stream);
        scatter_kernel<<<scatBlocks, blk, 0, stream>>>(h1, src, dst, agg, n_edges);
        linear_kernel<<<waveBlocks, blk, 0, stream>>>(h1, agg, deg, Ws2, Wn2, b2, out, n_nodes, 0);
    }
}

// Round 10
// 318.589 us; speedup vs baseline: 1.3920x; 1.3920x over previous
//
#include <hip/hip_runtime.h>

#define NF 64
#define BUCKET 128          // nodes per bucket (dstlocal = 7 bits)
#define MAXB 8192           // max buckets supported by LDS hist
#define CEPB 16384          // edges per block in bucket build (loop chunks)

typedef __attribute__((ext_vector_type(8))) short bf16x8;
typedef __attribute__((ext_vector_type(4))) float f32x4;
typedef __attribute__((ext_vector_type(4))) unsigned int u32x4;

__device__ __forceinline__ float bf2f(unsigned short x) {
    union { unsigned int u; float f; } v; v.u = ((unsigned int)x) << 16; return v.f;
}
__device__ __forceinline__ unsigned short f2bf(float x) {
    union { float f; unsigned int u; } v; v.f = x;
    unsigned int r = (v.u + 0x7FFFu + ((v.u >> 16) & 1u)) >> 16;
    return (unsigned short)r;
}

// =================== bucket build ===================

__global__ __launch_bounds__(256) void bhist_kernel(const int* __restrict__ dst,
                                                    int* __restrict__ bins,
                                                    int n_edges, int nb) {
    __shared__ int h[MAXB];
    for (int i = threadIdx.x; i < nb; i += 256) h[i] = 0;
    __syncthreads();
    int base = blockIdx.x * CEPB;
    int lim = min(base + CEPB, n_edges);
    for (int i = base + threadIdx.x; i < lim; i += 256)
        atomicAdd(&h[__builtin_nontemporal_load(dst + i) >> 7], 1);
    __syncthreads();
    for (int i = threadIdx.x; i < nb; i += 256) {
        int v = h[i];
        if (v) atomicAdd(&bins[i], v);
    }
}

__global__ __launch_bounds__(1024) void bscan_kernel(const int* __restrict__ bins,
                                                     int* __restrict__ bptr,
                                                     int* __restrict__ gcur, int nb) {
    __shared__ int sd[1024];
    int carry = 0;
    if (threadIdx.x == 0) bptr[0] = 0;
    for (int base = 0; base < nb; base += 1024) {
        int i = base + threadIdx.x;
        int v = (i < nb) ? bins[i] : 0;
        sd[threadIdx.x] = v;
        __syncthreads();
        for (int off = 1; off < 1024; off <<= 1) {
            int t = (threadIdx.x >= off) ? sd[threadIdx.x - off] : 0;
            __syncthreads();
            sd[threadIdx.x] += t;
            __syncthreads();
        }
        if (i < nb) {
            bptr[i + 1] = carry + sd[threadIdx.x];
            gcur[i] = carry + sd[threadIdx.x] - v;
        }
        int last = sd[1023];
        __syncthreads();
        carry += last;
    }
}

// two-pass counting scatter over CEPB-edge chunks; packed (src<<7)|(dst&127)
__global__ __launch_bounds__(256) void bscatter_kernel(const int* __restrict__ src,
                                                       const int* __restrict__ dst,
                                                       int* __restrict__ gcur,
                                                       unsigned* __restrict__ bedges,
                                                       int n_edges, int nb) {
    __shared__ int h[MAXB];
    for (int i = threadIdx.x; i < nb; i += 256) h[i] = 0;
    __syncthreads();
    int base = blockIdx.x * CEPB;
    int lim = min(base + CEPB, n_edges);
    for (int i = base + threadIdx.x; i < lim; i += 256)
        atomicAdd(&h[dst[i] >> 7], 1);
    __syncthreads();
    for (int i = threadIdx.x; i < nb; i += 256) {
        int v = h[i];
        h[i] = v ? atomicAdd(&gcur[i], v) : 0;
    }
    __syncthreads();
    for (int i = base + threadIdx.x; i < lim; i += 256) {
        int d = dst[i];
        int pos = atomicAdd(&h[d >> 7], 1);
        bedges[pos] = ((unsigned)src[i] << 7) | (unsigned)(d & 127);
    }
}

__global__ __launch_bounds__(256) void bfinal_kernel(
    const unsigned* __restrict__ bedges, const int* __restrict__ bptr,
    int* __restrict__ row_ptr, int* __restrict__ col,
    int n_nodes, int n_edges, int nb) {
    __shared__ int cnt[BUCKET];
    __shared__ int sa[BUCKET], sb2[BUCKET];
    int tid = threadIdx.x;
    int b = blockIdx.x;
    int beg = bptr[b], end = bptr[b + 1];
    if (tid < BUCKET) cnt[tid] = 0;
    __syncthreads();
    for (int i = beg + tid; i < end; i += 256)
        atomicAdd(&cnt[bedges[i] & (BUCKET - 1)], 1);
    __syncthreads();
    if (tid < BUCKET) sa[tid] = cnt[tid];
    __syncthreads();
    int* pin = sa; int* pout = sb2;
    for (int off = 1; off < BUCKET; off <<= 1) {
        if (tid < BUCKET) pout[tid] = pin[tid] + ((tid >= off) ? pin[tid - off] : 0);
        __syncthreads();
        int* t = pin; pin = pout; pout = t;
    }
    int nodeBase = b * BUCKET;
    if (tid < BUCKET && nodeBase + tid < n_nodes)
        row_ptr[nodeBase + tid] = beg + (tid ? pin[tid - 1] : 0);
    if (b == nb - 1 && tid == 0) row_ptr[n_nodes] = n_edges;
    __syncthreads();
    if (tid < BUCKET) cnt[tid] = 0;
    __syncthreads();
    for (int i = beg + tid; i < end; i += 256) {
        unsigned e = bedges[i];
        int d = e & (BUCKET - 1);
        int pos = beg + (d ? pin[d - 1] : 0) + atomicAdd(&cnt[d], 1);
        col[pos] = (int)(e >> 7);
    }
}

// =================== staging: convert + weight transpose in ONE dispatch ======
// blocks [0, convBlocks): features f32 [N][64] -> X[:,0:64] bf16 (stride 128)
// blocks [convBlocks, convBlocks+96): WT[layer][j][k] build
__global__ void stage_kernel(const float* __restrict__ in, unsigned short* __restrict__ X,
                             const float* __restrict__ Ws0, const float* __restrict__ Wn0,
                             const float* __restrict__ Ws1, const float* __restrict__ Wn1,
                             const float* __restrict__ Ws2, const float* __restrict__ Wn2,
                             unsigned short* __restrict__ WT, int n_nodes, int convBlocks) {
    if (blockIdx.x < (unsigned)convBlocks) {
        int t = blockIdx.x * 256 + threadIdx.x;
        int total = n_nodes * 16;
        if (t >= total) return;
        int n = t >> 4, g = t & 15;
        float4 v = *reinterpret_cast<const float4*>(in + (size_t)n * 64 + g * 4);
        ushort4 o;
        o.x = f2bf(v.x); o.y = f2bf(v.y); o.z = f2bf(v.z); o.w = f2bf(v.w);
        *reinterpret_cast<ushort4*>(X + (size_t)n * 128 + g * 4) = o;
    } else {
        int t = (blockIdx.x - convBlocks) * 256 + threadIdx.x;
        if (t >= 3 * 64 * 128) return;
        int layer = t >> 13;
        int r = t & 8191;
        int j = r >> 7, k = r & 127;
        const float* Ws = layer == 0 ? Ws0 : (layer == 1 ? Ws1 : Ws2);
        const float* Wn = layer == 0 ? Wn0 : (layer == 1 ? Wn1 : Wn2);
        float v = (k < 64) ? Ws[k * 64 + j] : Wn[(k - 64) * 64 + j];
        WT[t] = f2bf(v);
    }
}

// =================== aggregation (per-node CSR gather, oct-edge loads) =========
// one wave per node. 8 lanes cover one row (ushort8 = 8 features/lane = 16 B),
// so one load instruction gathers 8 edges (1 KB in flight). 2 loads unrolled =
// 16 edges/iter. Cross-group reduce: shfl_xor 8, 16, 32. deg = end - beg.
// col loads nontemporal: the 6.4MB col stream must not evict X rows from L2.
__global__ __launch_bounds__(256) void aggregate_bf16_kernel(
    unsigned short* __restrict__ X, const int* __restrict__ row_ptr, const int* __restrict__ col,
    int n_nodes) {
    int lane = threadIdx.x & 63;
    int wid = threadIdx.x >> 6;
    int q = lane >> 3;       // edge slot 0..7
    int j = lane & 7;        // feature oct (features 8j..8j+7)
    int n = blockIdx.x * 4 + wid;
    if (n >= n_nodes) return;
    int beg = row_ptr[n], end = row_ptr[n + 1];
    float a[8] = {0.f, 0.f, 0.f, 0.f, 0.f, 0.f, 0.f, 0.f};
    for (int i = beg; i < end; i += 16) {
        int e0 = i + q, e1 = i + 8 + q;
        bool ok0 = e0 < end, ok1 = e1 < end;
        int s0 = __builtin_nontemporal_load(col + (ok0 ? e0 : end - 1));
        int s1 = __builtin_nontemporal_load(col + (ok1 ? e1 : end - 1));
        u32x4 v0 = *reinterpret_cast<const u32x4*>(X + (size_t)s0 * 128 + j * 8);
        u32x4 v1 = *reinterpret_cast<const u32x4*>(X + (size_t)s1 * 128 + j * 8);
        if (ok0) {
#pragma unroll
            for (int k = 0; k < 4; ++k) {
                union { unsigned u; float f; } lo, hi;
                lo.u = v0[k] << 16; hi.u = v0[k] & 0xffff0000u;
                a[2 * k] += lo.f; a[2 * k + 1] += hi.f;
            }
        }
        if (ok1) {
#pragma unroll
            for (int k = 0; k < 4; ++k) {
                union { unsigned u; float f; } lo, hi;
                lo.u = v1[k] << 16; hi.u = v1[k] & 0xffff0000u;
                a[2 * k] += lo.f; a[2 * k + 1] += hi.f;
            }
        }
    }
#pragma unroll
    for (int k = 0; k < 8; ++k) {
        a[k] += __shfl_xor(a[k], 8);
        a[k] += __shfl_xor(a[k], 16);
        a[k] += __shfl_xor(a[k], 32);
    }
    if (q == 0) {
        float dinv = 1.0f / fmaxf((float)(end - beg), 1.0f);
        u32x4 o;
#pragma unroll
        for (int k = 0; k < 4; ++k)
            o[k] = ((unsigned)f2bf(a[2 * k + 1] * dinv) << 16) | f2bf(a[2 * k] * dinv);
        *reinterpret_cast<u32x4*>(X + (size_t)n * 128 + 64 + j * 8) = o;
    }
}

// =================== MFMA linear ===================
__global__ __launch_bounds__(256) void linear_mfma_kernel(
    const unsigned short* __restrict__ X, const unsigned short* __restrict__ WT,
    const float* __restrict__ bias, unsigned short* __restrict__ outBf,
    float* __restrict__ outF32, int n_nodes, int do_relu) {
    int lane = threadIdx.x & 63;
    int wid = threadIdx.x >> 6;
    int l15 = lane & 15;
    int lg = lane >> 4;

    bf16x8 wf[4][4];
#pragma unroll
    for (int ft = 0; ft < 4; ++ft)
#pragma unroll
        for (int ks = 0; ks < 4; ++ks)
            wf[ft][ks] = *reinterpret_cast<const bf16x8*>(
                WT + (size_t)(ft * 16 + l15) * 128 + ks * 32 + lg * 8);

    float4 bv[4];
#pragma unroll
    for (int ft = 0; ft < 4; ++ft)
        bv[ft] = *reinterpret_cast<const float4*>(bias + ft * 16 + lg * 4);

    int tiles = (n_nodes + 15) >> 4;
    for (int tile = blockIdx.x * 4 + wid; tile < tiles; tile += gridDim.x * 4) {
        int nodeBase = tile * 16;
        int nrow = nodeBase + l15;
        int rrow = nrow < n_nodes ? nrow : n_nodes - 1;

        bf16x8 xf[4];
#pragma unroll
        for (int ks = 0; ks < 4; ++ks)
            xf[ks] = *reinterpret_cast<const bf16x8*>(X + (size_t)rrow * 128 + ks * 32 + lg * 8);

        f32x4 acc[4];
#pragma unroll
        for (int ft = 0; ft < 4; ++ft) acc[ft] = (f32x4){0.f, 0.f, 0.f, 0.f};
#pragma unroll
        for (int ks = 0; ks < 4; ++ks) {
#pragma unroll
            for (int ft = 0; ft < 4; ++ft)
                acc[ft] = __builtin_amdgcn_mfma_f32_16x16x32_bf16(wf[ft][ks], xf[ks], acc[ft], 0, 0, 0);
        }

        if (nrow < n_nodes) {
#pragma unroll
            for (int ft = 0; ft < 4; ++ft) {
                float4 v;
                v.x = acc[ft][0] + bv[ft].x;
                v.y = acc[ft][1] + bv[ft].y;
                v.z = acc[ft][2] + bv[ft].z;
                v.w = acc[ft][3] + bv[ft].w;
                if (do_relu) {
                    v.x = fmaxf(v.x, 0.f); v.y = fmaxf(v.y, 0.f);
                    v.z = fmaxf(v.z, 0.f); v.w = fmaxf(v.w, 0.f);
                }
                int fbase = ft * 16 + lg * 4;
                if (outF32) {
                    *reinterpret_cast<float4*>(outF32 + (size_t)nrow * 64 + fbase) = v;
                } else {
                    ushort4 o;
                    o.x = f2bf(v.x); o.y = f2bf(v.y); o.z = f2bf(v.z); o.w = f2bf(v.w);
                    *reinterpret_cast<ushort4*>(outBf + (size_t)nrow * 128 + fbase) = o;
                }
            }
        }
    }
}

// =================== fallback (round-1 atomic scatter, f32) ===================

__global__ void deg_kernel(const int* __restrict__ dst, float* __restrict__ deg, int n_edges) {
    int e = blockIdx.x * blockDim.x + threadIdx.x;
    if (e < n_edges) unsafeAtomicAdd(&deg[dst[e]], 1.0f);
}

__global__ void inv_kernel(float* __restrict__ deg, int n) {
    int i = blockIdx.x * blockDim.x + threadIdx.x;
    if (i < n) deg[i] = 1.0f / fmaxf(deg[i], 1.0f);
}

__global__ __launch_bounds__(256) void scatter_kernel(
    const float* __restrict__ h, const int* __restrict__ src, const int* __restrict__ dst,
    float* __restrict__ agg, int n_edges) {
    int t = blockIdx.x * blockDim.x + threadIdx.x;
    int e = t >> 4;
    if (e >= n_edges) return;
    int q = (t & 15) * 4;
    int s = src[e];
    int d = dst[e];
    float4 v = *reinterpret_cast<const float4*>(h + (size_t)s * NF + q);
    float* o = agg + (size_t)d * NF + q;
    unsafeAtomicAdd(o + 0, v.x);
    unsafeAtomicAdd(o + 1, v.y);
    unsafeAtomicAdd(o + 2, v.z);
    unsafeAtomicAdd(o + 3, v.w);
}

__global__ __launch_bounds__(256) void linear_kernel(
    const float* __restrict__ h, const float* __restrict__ agg, const float* __restrict__ deginv,
    const float* __restrict__ Ws, const float* __restrict__ Wn, const float* __restrict__ bias,
    float* __restrict__ out, int n_nodes, int do_relu) {
    __shared__ float sWs[NF * NF];
    __shared__ float sWn[NF * NF];
    __shared__ float sb[NF];
    for (int i = threadIdx.x; i < NF * NF; i += 256) {
        sWs[i] = Ws[i];
        sWn[i] = Wn[i];
    }
    if (threadIdx.x < NF) sb[threadIdx.x] = bias[threadIdx.x];
    __syncthreads();
    int j = threadIdx.x & 63;
    int sub = threadIdx.x >> 6;
    for (int n = blockIdx.x * 4 + sub; n < n_nodes; n += gridDim.x * 4) {
        const float4* hr = reinterpret_cast<const float4*>(h + (size_t)n * NF);
        const float4* ar = reinterpret_cast<const float4*>(agg + (size_t)n * NF);
        float accS = 0.f, accN = 0.f;
#pragma unroll
        for (int k4 = 0; k4 < 16; ++k4) {
            float4 hv = hr[k4];
            float4 av = ar[k4];
            int kb = k4 * 4;
            accS += hv.x * sWs[(kb + 0) * NF + j];
            accN += av.x * sWn[(kb + 0) * NF + j];
            accS += hv.y * sWs[(kb + 1) * NF + j];
            accN += av.y * sWn[(kb + 1) * NF + j];
            accS += hv.z * sWs[(kb + 2) * NF + j];
            accN += av.z * sWn[(kb + 2) * NF + j];
            accS += hv.w * sWs[(kb + 3) * NF + j];
            accN += av.w * sWn[(kb + 3) * NF + j];
        }
        float val = accS + deginv[n] * accN + sb[j];
        if (do_relu) val = fmaxf(val, 0.f);
        out[(size_t)n * NF + j] = val;
    }
}

// =================== launch ===================

extern "C" void kernel_launch(void* const* d_in, const int* in_sizes, int n_in,
                              void* d_out, int out_size, void* d_ws, size_t ws_size,
                              hipStream_t stream) {
    const float* features = (const float*)d_in[0];
    const int* src = (const int*)d_in[1];
    const int* dst = (const int*)d_in[2];
    const float* Ws0 = (const float*)d_in[3];
    const float* Wn0 = (const float*)d_in[4];
    const float* b0  = (const float*)d_in[5];
    const float* Ws1 = (const float*)d_in[6];
    const float* Wn1 = (const float*)d_in[7];
    const float* b1  = (const float*)d_in[8];
    const float* Ws2 = (const float*)d_in[9];
    const float* Wn2 = (const float*)d_in[10];
    const float* b2  = (const float*)d_in[11];

    const int n_nodes = in_sizes[0] / NF;
    const int n_edges = in_sizes[1];
    float* out = (float*)d_out;

    const int nb = (n_nodes + BUCKET - 1) / BUCKET;
    const size_t alignNB = (((size_t)nb + 1) * 4 + 255) / 256 * 256;
    const size_t alignN = (((size_t)n_nodes + 64) * 4 + 255) / 256 * 256;
    const size_t alignE = ((size_t)n_edges * 4 + 255) / 256 * 256;
    const size_t xBytes = ((size_t)n_nodes * 128 * 2 + 255) / 256 * 256;
    const size_t wtBytes = 3 * 64 * 128 * 2;

    dim3 blk(256);
    const int nCB = (n_edges + CEPB - 1) / CEPB;
    const int waveBlocks = (n_nodes + 3) / 4;
    const int tiles = (n_nodes + 15) / 16;
    const int linBlocks = (tiles + 3) / 4;
    const int convBlocks = (n_nodes * 16 + 255) / 256;

    // ws layout: bins | bptr | gcur | row_ptr | col | X0 | X1 | WTall
    const size_t need = 3 * alignNB + alignN + alignE + 2 * xBytes + wtBytes;
    const bool outFits = (size_t)out_size * sizeof(float) >= (size_t)n_edges * sizeof(unsigned);

    if (ws_size >= need && nb <= MAXB && n_nodes < (1 << 25) && outFits) {
        char* ws = (char*)d_ws;
        int* bins     = (int*)ws;
        int* bptr     = (int*)(ws + alignNB);
        int* gcur     = (int*)(ws + 2 * alignNB);
        int* row_ptr  = (int*)(ws + 3 * alignNB);
        int* col      = (int*)(ws + 3 * alignNB + alignN);
        unsigned short* X0  = (unsigned short*)(ws + 3 * alignNB + alignN + alignE);
        unsigned short* X1  = (unsigned short*)((char*)X0 + xBytes);
        unsigned short* WT  = (unsigned short*)((char*)X1 + xBytes);
        unsigned short* WT0 = WT;
        unsigned short* WT1 = WT + 64 * 128;
        unsigned short* WT2 = WT + 2 * 64 * 128;
        unsigned* bedges = (unsigned*)d_out;   // dead before final linear writes d_out

        // bucket build
        hipMemsetAsync(bins, 0, (size_t)nb * sizeof(int), stream);
        bhist_kernel<<<nCB, blk, 0, stream>>>(dst, bins, n_edges, nb);
        bscan_kernel<<<1, 1024, 0, stream>>>(bins, bptr, gcur, nb);
        bscatter_kernel<<<nCB, blk, 0, stream>>>(src, dst, gcur, bedges, n_edges, nb);
        bfinal_kernel<<<nb, blk, 0, stream>>>(bedges, bptr, row_ptr, col, n_nodes, n_edges, nb);

        // staging (convert + weight transpose, one dispatch)
        stage_kernel<<<convBlocks + 96, blk, 0, stream>>>(features, X0,
            Ws0, Wn0, Ws1, Wn1, Ws2, Wn2, WT, n_nodes, convBlocks);

        // layer 0: X0 -> X1
        aggregate_bf16_kernel<<<waveBlocks, blk, 0, stream>>>(X0, row_ptr, col, n_nodes);
        linear_mfma_kernel<<<linBlocks, blk, 0, stream>>>(X0, WT0, b0, X1, nullptr, n_nodes, 1);
        // layer 1: X1 -> X0
        aggregate_bf16_kernel<<<waveBlocks, blk, 0, stream>>>(X1, row_ptr, col, n_nodes);
        linear_mfma_kernel<<<linBlocks, blk, 0, stream>>>(X1, WT1, b1, X0, nullptr, n_nodes, 1);
        // layer 2: X0 -> d_out (f32)
        aggregate_bf16_kernel<<<waveBlocks, blk, 0, stream>>>(X0, row_ptr, col, n_nodes);
        linear_mfma_kernel<<<linBlocks, blk, 0, stream>>>(X0, WT2, b2, nullptr, out, n_nodes, 0);
    } else {
        // fallback: atomic-scatter path (f32)
        char* ws = (char*)d_ws;
        size_t degBytes = (((size_t)n_nodes * 4) + 255) / 256 * 256;
        float* deg = (float*)ws;
        float* agg = (float*)(ws + degBytes);
        float* h1  = agg + (size_t)n_nodes * NF;
        int scatBlocks = (n_edges * 16 + 255) / 256;
        int eBlocks = (n_edges + 255) / 256;
        size_t rowBytes = (size_t)n_nodes * NF * sizeof(float);

        hipMemsetAsync(deg, 0, (size_t)n_nodes * sizeof(float), stream);
        deg_kernel<<<eBlocks, blk, 0, stream>>>(dst, deg, n_edges);
        inv_kernel<<<(n_nodes + 255) / 256, blk, 0, stream>>>(deg, n_nodes);

        hipMemsetAsync(agg, 0, rowBytes, stream);
        scatter_kernel<<<scatBlocks, blk, 0, stream>>>(features, src, dst, agg, n_edges);
        linear_kernel<<<waveBlocks, blk, 0, stream>>>(features, agg, deg, Ws0, Wn0, b0, out, n_nodes, 1);

        hipMemsetAsync(agg, 0, rowBytes, stream);
        scatter_kernel<<<scatBlocks, blk, 0, stream>>>(out, src, dst, agg, n_edges);
        linear_kernel<<<waveBlocks, blk, 0, stream>>>(out, agg, deg, Ws1, Wn1, b1, h1, n_nodes, 1);

        hipMemsetAsync(agg, 0, rowBytes, stream);
        scatter_kernel<<<scatBlocks, blk, 0, stream>>>(h1, src, dst, agg, n_edges);
        linear_kernel<<<waveBlocks, blk, 0, stream>>>(h1, agg, deg, Ws2, Wn2, b2, out, n_nodes, 0);
    }
}

// Round 11
// 273.982 us; speedup vs baseline: 1.6186x; 1.1628x over previous
//
#include <hip/hip_runtime.h>

#define NF 64
#define BUCKET 128          // nodes per bucket (dstlocal = 7 bits)
#define MAXB 8192           // max buckets supported by LDS hist
#define EPB 4096            // edges per block in bucket build

typedef __attribute__((ext_vector_type(8))) short bf16x8;
typedef __attribute__((ext_vector_type(4))) float f32x4;
typedef __attribute__((ext_vector_type(4))) unsigned int u32x4;

__device__ __forceinline__ float bf2f(unsigned short x) {
    union { unsigned int u; float f; } v; v.u = ((unsigned int)x) << 16; return v.f;
}
__device__ __forceinline__ unsigned short f2bf(float x) {
    union { float f; unsigned int u; } v; v.f = x;
    unsigned int r = (v.u + 0x7FFFu + ((v.u >> 16) & 1u)) >> 16;
    return (unsigned short)r;
}

// =================== bucket build (R7 structure: 391 blocks, reg-cached) ======

__global__ __launch_bounds__(256) void bhist_kernel(const int* __restrict__ dst,
                                                    int* __restrict__ bins,
                                                    int n_edges, int nb) {
    __shared__ int h[MAXB];
    for (int i = threadIdx.x; i < nb; i += 256) h[i] = 0;
    __syncthreads();
    int base = blockIdx.x * EPB;
    int lim = min(base + EPB, n_edges);
    for (int i = base + threadIdx.x; i < lim; i += 256)
        atomicAdd(&h[dst[i] >> 7], 1);
    __syncthreads();
    for (int i = threadIdx.x; i < nb; i += 256) {
        int v = h[i];
        if (v) atomicAdd(&bins[i], v);
    }
}

__global__ __launch_bounds__(1024) void bscan_kernel(const int* __restrict__ bins,
                                                     int* __restrict__ bptr,
                                                     int* __restrict__ gcur, int nb) {
    __shared__ int sd[1024];
    int carry = 0;
    if (threadIdx.x == 0) bptr[0] = 0;
    for (int base = 0; base < nb; base += 1024) {
        int i = base + threadIdx.x;
        int v = (i < nb) ? bins[i] : 0;
        sd[threadIdx.x] = v;
        __syncthreads();
        for (int off = 1; off < 1024; off <<= 1) {
            int t = (threadIdx.x >= off) ? sd[threadIdx.x - off] : 0;
            __syncthreads();
            sd[threadIdx.x] += t;
            __syncthreads();
        }
        if (i < nb) {
            bptr[i + 1] = carry + sd[threadIdx.x];
            gcur[i] = carry + sd[threadIdx.x] - v;
        }
        int last = sd[1023];
        __syncthreads();
        carry += last;
    }
}

// two-level counting scatter: packed entry (src << 7) | (dst & 127)
__global__ __launch_bounds__(256) void bscatter_kernel(const int* __restrict__ src,
                                                       const int* __restrict__ dst,
                                                       int* __restrict__ gcur,
                                                       unsigned* __restrict__ bedges,
                                                       int n_edges, int nb) {
    __shared__ int h[MAXB];
    for (int i = threadIdx.x; i < nb; i += 256) h[i] = 0;
    __syncthreads();
    int base = blockIdx.x * EPB;
    int myDst[16], mySrc[16];
#pragma unroll
    for (int k = 0; k < 16; ++k) {
        int i = base + k * 256 + threadIdx.x;
        if (i < n_edges) {
            myDst[k] = dst[i];
            mySrc[k] = src[i];
            atomicAdd(&h[myDst[k] >> 7], 1);
        } else {
            myDst[k] = -1;
        }
    }
    __syncthreads();
    for (int i = threadIdx.x; i < nb; i += 256) {
        int v = h[i];
        h[i] = v ? atomicAdd(&gcur[i], v) : 0;
    }
    __syncthreads();
#pragma unroll
    for (int k = 0; k < 16; ++k) {
        if (myDst[k] >= 0) {
            int bin = myDst[k] >> 7;
            int pos = atomicAdd(&h[bin], 1);
            bedges[pos] = ((unsigned)mySrc[k] << 7) | (unsigned)(myDst[k] & 127);
        }
    }
}

__global__ __launch_bounds__(256) void bfinal_kernel(
    const unsigned* __restrict__ bedges, const int* __restrict__ bptr,
    int* __restrict__ row_ptr, int* __restrict__ col,
    int n_nodes, int n_edges, int nb) {
    __shared__ int cnt[BUCKET];
    __shared__ int sa[BUCKET], sb2[BUCKET];
    int tid = threadIdx.x;
    int b = blockIdx.x;
    int beg = bptr[b], end = bptr[b + 1];
    if (tid < BUCKET) cnt[tid] = 0;
    __syncthreads();
    for (int i = beg + tid; i < end; i += 256)
        atomicAdd(&cnt[bedges[i] & (BUCKET - 1)], 1);
    __syncthreads();
    if (tid < BUCKET) sa[tid] = cnt[tid];
    __syncthreads();
    int* pin = sa; int* pout = sb2;
    for (int off = 1; off < BUCKET; off <<= 1) {
        if (tid < BUCKET) pout[tid] = pin[tid] + ((tid >= off) ? pin[tid - off] : 0);
        __syncthreads();
        int* t = pin; pin = pout; pout = t;
    }
    int nodeBase = b * BUCKET;
    if (tid < BUCKET && nodeBase + tid < n_nodes)
        row_ptr[nodeBase + tid] = beg + (tid ? pin[tid - 1] : 0);
    if (b == nb - 1 && tid == 0) row_ptr[n_nodes] = n_edges;
    __syncthreads();
    if (tid < BUCKET) cnt[tid] = 0;
    __syncthreads();
    for (int i = beg + tid; i < end; i += 256) {
        unsigned e = bedges[i];
        int d = e & (BUCKET - 1);
        int pos = beg + (d ? pin[d - 1] : 0) + atomicAdd(&cnt[d], 1);
        col[pos] = (int)(e >> 7);
    }
}

// =================== staging: convert + weight transpose in ONE dispatch ======
__global__ void stage_kernel(const float* __restrict__ in, unsigned short* __restrict__ X,
                             const float* __restrict__ Ws0, const float* __restrict__ Wn0,
                             const float* __restrict__ Ws1, const float* __restrict__ Wn1,
                             const float* __restrict__ Ws2, const float* __restrict__ Wn2,
                             unsigned short* __restrict__ WT, int n_nodes, int convBlocks) {
    if (blockIdx.x < (unsigned)convBlocks) {
        int t = blockIdx.x * 256 + threadIdx.x;
        int total = n_nodes * 16;
        if (t >= total) return;
        int n = t >> 4, g = t & 15;
        float4 v = *reinterpret_cast<const float4*>(in + (size_t)n * 64 + g * 4);
        ushort4 o;
        o.x = f2bf(v.x); o.y = f2bf(v.y); o.z = f2bf(v.z); o.w = f2bf(v.w);
        *reinterpret_cast<ushort4*>(X + (size_t)n * 128 + g * 4) = o;
    } else {
        int t = (blockIdx.x - convBlocks) * 256 + threadIdx.x;
        if (t >= 3 * 64 * 128) return;
        int layer = t >> 13;
        int r = t & 8191;
        int j = r >> 7, k = r & 127;
        const float* Ws = layer == 0 ? Ws0 : (layer == 1 ? Ws1 : Ws2);
        const float* Wn = layer == 0 ? Wn0 : (layer == 1 ? Wn1 : Wn2);
        float v = (k < 64) ? Ws[k * 64 + j] : Wn[(k - 64) * 64 + j];
        WT[t] = f2bf(v);
    }
}

// =================== aggregation (per-node CSR gather, oct-edge loads) =========
__global__ __launch_bounds__(256) void aggregate_bf16_kernel(
    unsigned short* __restrict__ X, const int* __restrict__ row_ptr, const int* __restrict__ col,
    int n_nodes) {
    int lane = threadIdx.x & 63;
    int wid = threadIdx.x >> 6;
    int q = lane >> 3;       // edge slot 0..7
    int j = lane & 7;        // feature oct (features 8j..8j+7)
    int n = blockIdx.x * 4 + wid;
    if (n >= n_nodes) return;
    int beg = row_ptr[n], end = row_ptr[n + 1];
    float a[8] = {0.f, 0.f, 0.f, 0.f, 0.f, 0.f, 0.f, 0.f};
    for (int i = beg; i < end; i += 16) {
        int e0 = i + q, e1 = i + 8 + q;
        bool ok0 = e0 < end, ok1 = e1 < end;
        int s0 = __builtin_nontemporal_load(col + (ok0 ? e0 : end - 1));
        int s1 = __builtin_nontemporal_load(col + (ok1 ? e1 : end - 1));
        u32x4 v0 = *reinterpret_cast<const u32x4*>(X + (size_t)s0 * 128 + j * 8);
        u32x4 v1 = *reinterpret_cast<const u32x4*>(X + (size_t)s1 * 128 + j * 8);
        if (ok0) {
#pragma unroll
            for (int k = 0; k < 4; ++k) {
                union { unsigned u; float f; } lo, hi;
                lo.u = v0[k] << 16; hi.u = v0[k] & 0xffff0000u;
                a[2 * k] += lo.f; a[2 * k + 1] += hi.f;
            }
        }
        if (ok1) {
#pragma unroll
            for (int k = 0; k < 4; ++k) {
                union { unsigned u; float f; } lo, hi;
                lo.u = v1[k] << 16; hi.u = v1[k] & 0xffff0000u;
                a[2 * k] += lo.f; a[2 * k + 1] += hi.f;
            }
        }
    }
#pragma unroll
    for (int k = 0; k < 8; ++k) {
        a[k] += __shfl_xor(a[k], 8);
        a[k] += __shfl_xor(a[k], 16);
        a[k] += __shfl_xor(a[k], 32);
    }
    if (q == 0) {
        float dinv = 1.0f / fmaxf((float)(end - beg), 1.0f);
        u32x4 o;
#pragma unroll
        for (int k = 0; k < 4; ++k)
            o[k] = ((unsigned)f2bf(a[2 * k + 1] * dinv) << 16) | f2bf(a[2 * k] * dinv);
        *reinterpret_cast<u32x4*>(X + (size_t)n * 128 + 64 + j * 8) = o;
    }
}

// =================== MFMA linear ===================
__global__ __launch_bounds__(256) void linear_mfma_kernel(
    const unsigned short* __restrict__ X, const unsigned short* __restrict__ WT,
    const float* __restrict__ bias, unsigned short* __restrict__ outBf,
    float* __restrict__ outF32, int n_nodes, int do_relu) {
    int lane = threadIdx.x & 63;
    int wid = threadIdx.x >> 6;
    int l15 = lane & 15;
    int lg = lane >> 4;

    bf16x8 wf[4][4];
#pragma unroll
    for (int ft = 0; ft < 4; ++ft)
#pragma unroll
        for (int ks = 0; ks < 4; ++ks)
            wf[ft][ks] = *reinterpret_cast<const bf16x8*>(
                WT + (size_t)(ft * 16 + l15) * 128 + ks * 32 + lg * 8);

    float4 bv[4];
#pragma unroll
    for (int ft = 0; ft < 4; ++ft)
        bv[ft] = *reinterpret_cast<const float4*>(bias + ft * 16 + lg * 4);

    int tiles = (n_nodes + 15) >> 4;
    for (int tile = blockIdx.x * 4 + wid; tile < tiles; tile += gridDim.x * 4) {
        int nodeBase = tile * 16;
        int nrow = nodeBase + l15;
        int rrow = nrow < n_nodes ? nrow : n_nodes - 1;

        bf16x8 xf[4];
#pragma unroll
        for (int ks = 0; ks < 4; ++ks)
            xf[ks] = *reinterpret_cast<const bf16x8*>(X + (size_t)rrow * 128 + ks * 32 + lg * 8);

        f32x4 acc[4];
#pragma unroll
        for (int ft = 0; ft < 4; ++ft) acc[ft] = (f32x4){0.f, 0.f, 0.f, 0.f};
#pragma unroll
        for (int ks = 0; ks < 4; ++ks) {
#pragma unroll
            for (int ft = 0; ft < 4; ++ft)
                acc[ft] = __builtin_amdgcn_mfma_f32_16x16x32_bf16(wf[ft][ks], xf[ks], acc[ft], 0, 0, 0);
        }

        if (nrow < n_nodes) {
#pragma unroll
            for (int ft = 0; ft < 4; ++ft) {
                float4 v;
                v.x = acc[ft][0] + bv[ft].x;
                v.y = acc[ft][1] + bv[ft].y;
                v.z = acc[ft][2] + bv[ft].z;
                v.w = acc[ft][3] + bv[ft].w;
                if (do_relu) {
                    v.x = fmaxf(v.x, 0.f); v.y = fmaxf(v.y, 0.f);
                    v.z = fmaxf(v.z, 0.f); v.w = fmaxf(v.w, 0.f);
                }
                int fbase = ft * 16 + lg * 4;
                if (outF32) {
                    *reinterpret_cast<float4*>(outF32 + (size_t)nrow * 64 + fbase) = v;
                } else {
                    ushort4 o;
                    o.x = f2bf(v.x); o.y = f2bf(v.y); o.z = f2bf(v.z); o.w = f2bf(v.w);
                    *reinterpret_cast<ushort4*>(outBf + (size_t)nrow * 128 + fbase) = o;
                }
            }
        }
    }
}

// =================== fallback (round-1 atomic scatter, f32) ===================

__global__ void deg_kernel(const int* __restrict__ dst, float* __restrict__ deg, int n_edges) {
    int e = blockIdx.x * blockDim.x + threadIdx.x;
    if (e < n_edges) unsafeAtomicAdd(&deg[dst[e]], 1.0f);
}

__global__ void inv_kernel(float* __restrict__ deg, int n) {
    int i = blockIdx.x * blockDim.x + threadIdx.x;
    if (i < n) deg[i] = 1.0f / fmaxf(deg[i], 1.0f);
}

__global__ __launch_bounds__(256) void scatter_kernel(
    const float* __restrict__ h, const int* __restrict__ src, const int* __restrict__ dst,
    float* __restrict__ agg, int n_edges) {
    int t = blockIdx.x * blockDim.x + threadIdx.x;
    int e = t >> 4;
    if (e >= n_edges) return;
    int q = (t & 15) * 4;
    int s = src[e];
    int d = dst[e];
    float4 v = *reinterpret_cast<const float4*>(h + (size_t)s * NF + q);
    float* o = agg + (size_t)d * NF + q;
    unsafeAtomicAdd(o + 0, v.x);
    unsafeAtomicAdd(o + 1, v.y);
    unsafeAtomicAdd(o + 2, v.z);
    unsafeAtomicAdd(o + 3, v.w);
}

__global__ __launch_bounds__(256) void linear_kernel(
    const float* __restrict__ h, const float* __restrict__ agg, const float* __restrict__ deginv,
    const float* __restrict__ Ws, const float* __restrict__ Wn, const float* __restrict__ bias,
    float* __restrict__ out, int n_nodes, int do_relu) {
    __shared__ float sWs[NF * NF];
    __shared__ float sWn[NF * NF];
    __shared__ float sb[NF];
    for (int i = threadIdx.x; i < NF * NF; i += 256) {
        sWs[i] = Ws[i];
        sWn[i] = Wn[i];
    }
    if (threadIdx.x < NF) sb[threadIdx.x] = bias[threadIdx.x];
    __syncthreads();
    int j = threadIdx.x & 63;
    int sub = threadIdx.x >> 6;
    for (int n = blockIdx.x * 4 + sub; n < n_nodes; n += gridDim.x * 4) {
        const float4* hr = reinterpret_cast<const float4*>(h + (size_t)n * NF);
        const float4* ar = reinterpret_cast<const float4*>(agg + (size_t)n * NF);
        float accS = 0.f, accN = 0.f;
#pragma unroll
        for (int k4 = 0; k4 < 16; ++k4) {
            float4 hv = hr[k4];
            float4 av = ar[k4];
            int kb = k4 * 4;
            accS += hv.x * sWs[(kb + 0) * NF + j];
            accN += av.x * sWn[(kb + 0) * NF + j];
            accS += hv.y * sWs[(kb + 1) * NF + j];
            accN += av.y * sWn[(kb + 1) * NF + j];
            accS += hv.z * sWs[(kb + 2) * NF + j];
            accN += av.z * sWn[(kb + 2) * NF + j];
            accS += hv.w * sWs[(kb + 3) * NF + j];
            accN += av.w * sWn[(kb + 3) * NF + j];
        }
        float val = accS + deginv[n] * accN + sb[j];
        if (do_relu) val = fmaxf(val, 0.f);
        out[(size_t)n * NF + j] = val;
    }
}

// =================== launch ===================

extern "C" void kernel_launch(void* const* d_in, const int* in_sizes, int n_in,
                              void* d_out, int out_size, void* d_ws, size_t ws_size,
                              hipStream_t stream) {
    const float* features = (const float*)d_in[0];
    const int* src = (const int*)d_in[1];
    const int* dst = (const int*)d_in[2];
    const float* Ws0 = (const float*)d_in[3];
    const float* Wn0 = (const float*)d_in[4];
    const float* b0  = (const float*)d_in[5];
    const float* Ws1 = (const float*)d_in[6];
    const float* Wn1 = (const float*)d_in[7];
    const float* b1  = (const float*)d_in[8];
    const float* Ws2 = (const float*)d_in[9];
    const float* Wn2 = (const float*)d_in[10];
    const float* b2  = (const float*)d_in[11];

    const int n_nodes = in_sizes[0] / NF;
    const int n_edges = in_sizes[1];
    float* out = (float*)d_out;

    const int nb = (n_nodes + BUCKET - 1) / BUCKET;
    const size_t alignNB = (((size_t)nb + 1) * 4 + 255) / 256 * 256;
    const size_t alignN = (((size_t)n_nodes + 64) * 4 + 255) / 256 * 256;
    const size_t alignE = ((size_t)n_edges * 4 + 255) / 256 * 256;
    const size_t xBytes = ((size_t)n_nodes * 128 * 2 + 255) / 256 * 256;
    const size_t wtBytes = 3 * 64 * 128 * 2;

    dim3 blk(256);
    const int nEB = (n_edges + EPB - 1) / EPB;
    const int waveBlocks = (n_nodes + 3) / 4;
    const int tiles = (n_nodes + 15) / 16;
    const int linBlocks = (tiles + 3) / 4;
    const int convBlocks = (n_nodes * 16 + 255) / 256;

    // ws layout: bins | bptr | gcur | row_ptr | col | X0 | X1 | WTall
    const size_t need = 3 * alignNB + alignN + alignE + 2 * xBytes + wtBytes;
    const bool outFits = (size_t)out_size * sizeof(float) >= (size_t)n_edges * sizeof(unsigned);

    if (ws_size >= need && nb <= MAXB && n_nodes < (1 << 25) && outFits) {
        char* ws = (char*)d_ws;
        int* bins     = (int*)ws;
        int* bptr     = (int*)(ws + alignNB);
        int* gcur     = (int*)(ws + 2 * alignNB);
        int* row_ptr  = (int*)(ws + 3 * alignNB);
        int* col      = (int*)(ws + 3 * alignNB + alignN);
        unsigned short* X0  = (unsigned short*)(ws + 3 * alignNB + alignN + alignE);
        unsigned short* X1  = (unsigned short*)((char*)X0 + xBytes);
        unsigned short* WT  = (unsigned short*)((char*)X1 + xBytes);
        unsigned short* WT0 = WT;
        unsigned short* WT1 = WT + 64 * 128;
        unsigned short* WT2 = WT + 2 * 64 * 128;
        unsigned* bedges = (unsigned*)d_out;   // dead before final linear writes d_out

        // bucket build
        hipMemsetAsync(bins, 0, (size_t)nb * sizeof(int), stream);
        bhist_kernel<<<nEB, blk, 0, stream>>>(dst, bins, n_edges, nb);
        bscan_kernel<<<1, 1024, 0, stream>>>(bins, bptr, gcur, nb);
        bscatter_kernel<<<nEB, blk, 0, stream>>>(src, dst, gcur, bedges, n_edges, nb);
        bfinal_kernel<<<nb, blk, 0, stream>>>(bedges, bptr, row_ptr, col, n_nodes, n_edges, nb);

        // staging (convert + weight transpose, one dispatch)
        stage_kernel<<<convBlocks + 96, blk, 0, stream>>>(features, X0,
            Ws0, Wn0, Ws1, Wn1, Ws2, Wn2, WT, n_nodes, convBlocks);

        // layer 0: X0 -> X1
        aggregate_bf16_kernel<<<waveBlocks, blk, 0, stream>>>(X0, row_ptr, col, n_nodes);
        linear_mfma_kernel<<<linBlocks, blk, 0, stream>>>(X0, WT0, b0, X1, nullptr, n_nodes, 1);
        // layer 1: X1 -> X0
        aggregate_bf16_kernel<<<waveBlocks, blk, 0, stream>>>(X1, row_ptr, col, n_nodes);
        linear_mfma_kernel<<<linBlocks, blk, 0, stream>>>(X1, WT1, b1, X0, nullptr, n_nodes, 1);
        // layer 2: X0 -> d_out (f32)
        aggregate_bf16_kernel<<<waveBlocks, blk, 0, stream>>>(X0, row_ptr, col, n_nodes);
        linear_mfma_kernel<<<linBlocks, blk, 0, stream>>>(X0, WT2, b2, nullptr, out, n_nodes, 0);
    } else {
        // fallback: atomic-scatter path (f32)
        char* ws = (char*)d_ws;
        size_t degBytes = (((size_t)n_nodes * 4) + 255) / 256 * 256;
        float* deg = (float*)ws;
        float* agg = (float*)(ws + degBytes);
        float* h1  = agg + (size_t)n_nodes * NF;
        int scatBlocks = (n_edges * 16 + 255) / 256;
        int eBlocks = (n_edges + 255) / 256;
        size_t rowBytes = (size_t)n_nodes * NF * sizeof(float);

        hipMemsetAsync(deg, 0, (size_t)n_nodes * sizeof(float), stream);
        deg_kernel<<<eBlocks, blk, 0, stream>>>(dst, deg, n_edges);
        inv_kernel<<<(n_nodes + 255) / 256, blk, 0, stream>>>(deg, n_nodes);

        hipMemsetAsync(agg, 0, rowBytes, stream);
        scatter_kernel<<<scatBlocks, blk, 0, stream>>>(features, src, dst, agg, n_edges);
        linear_kernel<<<waveBlocks, blk, 0, stream>>>(features, agg, deg, Ws0, Wn0, b0, out, n_nodes, 1);

        hipMemsetAsync(agg, 0, rowBytes, stream);
        scatter_kernel<<<scatBlocks, blk, 0, stream>>>(out, src, dst, agg, n_edges);
        linear_kernel<<<waveBlocks, blk, 0, stream>>>(out, agg, deg, Ws1, Wn1, b1, h1, n_nodes, 1);

        hipMemsetAsync(agg, 0, rowBytes, stream);
        scatter_kernel<<<scatBlocks, blk, 0, stream>>>(h1, src, dst, agg, n_edges);
        linear_kernel<<<waveBlocks, blk, 0, stream>>>(h1, agg, deg, Ws2, Wn2, b2, out, n_nodes, 0);
    }
}

// Round 12
// 257.290 us; speedup vs baseline: 1.7236x; 1.0649x over previous
//
#include <hip/hip_runtime.h>

#define NF 64
#define BUCKET 128          // nodes per bucket (dstlocal = 7 bits)
#define MAXB 8192           // max buckets supported by LDS hist
#define EPB 4096            // edges per block in bucket build

typedef __attribute__((ext_vector_type(8))) short bf16x8;
typedef __attribute__((ext_vector_type(4))) float f32x4;
typedef __attribute__((ext_vector_type(4))) unsigned int u32x4;

__device__ __forceinline__ float bf2f(unsigned short x) {
    union { unsigned int u; float f; } v; v.u = ((unsigned int)x) << 16; return v.f;
}
__device__ __forceinline__ unsigned short f2bf(float x) {
    union { float f; unsigned int u; } v; v.f = x;
    unsigned int r = (v.u + 0x7FFFu + ((v.u >> 16) & 1u)) >> 16;
    return (unsigned short)r;
}

// =================== bucket build (R7 structure: 391 blocks, reg-cached) ======

__global__ __launch_bounds__(256) void bhist_kernel(const int* __restrict__ dst,
                                                    int* __restrict__ bins,
                                                    int n_edges, int nb) {
    __shared__ int h[MAXB];
    for (int i = threadIdx.x; i < nb; i += 256) h[i] = 0;
    __syncthreads();
    int base = blockIdx.x * EPB;
    int lim = min(base + EPB, n_edges);
    for (int i = base + threadIdx.x; i < lim; i += 256)
        atomicAdd(&h[dst[i] >> 7], 1);
    __syncthreads();
    for (int i = threadIdx.x; i < nb; i += 256) {
        int v = h[i];
        if (v) atomicAdd(&bins[i], v);
    }
}

__global__ __launch_bounds__(1024) void bscan_kernel(const int* __restrict__ bins,
                                                     int* __restrict__ bptr,
                                                     int* __restrict__ gcur, int nb) {
    __shared__ int sd[1024];
    int carry = 0;
    if (threadIdx.x == 0) bptr[0] = 0;
    for (int base = 0; base < nb; base += 1024) {
        int i = base + threadIdx.x;
        int v = (i < nb) ? bins[i] : 0;
        sd[threadIdx.x] = v;
        __syncthreads();
        for (int off = 1; off < 1024; off <<= 1) {
            int t = (threadIdx.x >= off) ? sd[threadIdx.x - off] : 0;
            __syncthreads();
            sd[threadIdx.x] += t;
            __syncthreads();
        }
        if (i < nb) {
            bptr[i + 1] = carry + sd[threadIdx.x];
            gcur[i] = carry + sd[threadIdx.x] - v;
        }
        int last = sd[1023];
        __syncthreads();
        carry += last;
    }
}

// two-level counting scatter: packed entry (src << 7) | (dst & 127)
__global__ __launch_bounds__(256) void bscatter_kernel(const int* __restrict__ src,
                                                       const int* __restrict__ dst,
                                                       int* __restrict__ gcur,
                                                       unsigned* __restrict__ bedges,
                                                       int n_edges, int nb) {
    __shared__ int h[MAXB];
    for (int i = threadIdx.x; i < nb; i += 256) h[i] = 0;
    __syncthreads();
    int base = blockIdx.x * EPB;
    int myDst[16], mySrc[16];
#pragma unroll
    for (int k = 0; k < 16; ++k) {
        int i = base + k * 256 + threadIdx.x;
        if (i < n_edges) {
            myDst[k] = dst[i];
            mySrc[k] = src[i];
            atomicAdd(&h[myDst[k] >> 7], 1);
        } else {
            myDst[k] = -1;
        }
    }
    __syncthreads();
    for (int i = threadIdx.x; i < nb; i += 256) {
        int v = h[i];
        h[i] = v ? atomicAdd(&gcur[i], v) : 0;
    }
    __syncthreads();
#pragma unroll
    for (int k = 0; k < 16; ++k) {
        if (myDst[k] >= 0) {
            int bin = myDst[k] >> 7;
            int pos = atomicAdd(&h[bin], 1);
            bedges[pos] = ((unsigned)mySrc[k] << 7) | (unsigned)(myDst[k] & 127);
        }
    }
}

__global__ __launch_bounds__(256) void bfinal_kernel(
    const unsigned* __restrict__ bedges, const int* __restrict__ bptr,
    int* __restrict__ row_ptr, int* __restrict__ col,
    int n_nodes, int n_edges, int nb) {
    __shared__ int cnt[BUCKET];
    __shared__ int sa[BUCKET], sb2[BUCKET];
    int tid = threadIdx.x;
    int b = blockIdx.x;
    int beg = bptr[b], end = bptr[b + 1];
    if (tid < BUCKET) cnt[tid] = 0;
    __syncthreads();
    for (int i = beg + tid; i < end; i += 256)
        atomicAdd(&cnt[bedges[i] & (BUCKET - 1)], 1);
    __syncthreads();
    if (tid < BUCKET) sa[tid] = cnt[tid];
    __syncthreads();
    int* pin = sa; int* pout = sb2;
    for (int off = 1; off < BUCKET; off <<= 1) {
        if (tid < BUCKET) pout[tid] = pin[tid] + ((tid >= off) ? pin[tid - off] : 0);
        __syncthreads();
        int* t = pin; pin = pout; pout = t;
    }
    int nodeBase = b * BUCKET;
    if (tid < BUCKET && nodeBase + tid < n_nodes)
        row_ptr[nodeBase + tid] = beg + (tid ? pin[tid - 1] : 0);
    if (b == nb - 1 && tid == 0) row_ptr[n_nodes] = n_edges;
    __syncthreads();
    if (tid < BUCKET) cnt[tid] = 0;
    __syncthreads();
    for (int i = beg + tid; i < end; i += 256) {
        unsigned e = bedges[i];
        int d = e & (BUCKET - 1);
        int pos = beg + (d ? pin[d - 1] : 0) + atomicAdd(&cnt[d], 1);
        col[pos] = (int)(e >> 7);
    }
}

// =================== staging: convert + weight transpose in ONE dispatch ======
__global__ void stage_kernel(const float* __restrict__ in, unsigned short* __restrict__ X,
                             const float* __restrict__ Ws0, const float* __restrict__ Wn0,
                             const float* __restrict__ Ws1, const float* __restrict__ Wn1,
                             const float* __restrict__ Ws2, const float* __restrict__ Wn2,
                             unsigned short* __restrict__ WT, int n_nodes, int convBlocks) {
    if (blockIdx.x < (unsigned)convBlocks) {
        int t = blockIdx.x * 256 + threadIdx.x;
        int total = n_nodes * 16;
        if (t >= total) return;
        int n = t >> 4, g = t & 15;
        float4 v = *reinterpret_cast<const float4*>(in + (size_t)n * 64 + g * 4);
        ushort4 o;
        o.x = f2bf(v.x); o.y = f2bf(v.y); o.z = f2bf(v.z); o.w = f2bf(v.w);
        *reinterpret_cast<ushort4*>(X + (size_t)n * 128 + g * 4) = o;
    } else {
        int t = (blockIdx.x - convBlocks) * 256 + threadIdx.x;
        if (t >= 3 * 64 * 128) return;
        int layer = t >> 13;
        int r = t & 8191;
        int j = r >> 7, k = r & 127;
        const float* Ws = layer == 0 ? Ws0 : (layer == 1 ? Ws1 : Ws2);
        const float* Wn = layer == 0 ? Wn0 : (layer == 1 ? Wn1 : Wn2);
        float v = (k < 64) ? Ws[k * 64 + j] : Wn[(k - 64) * 64 + j];
        WT[t] = f2bf(v);
    }
}

// =================== aggregation (per-node CSR gather, oct-edge loads) =========
// one wave per node. 8 lanes cover one row (ushort8 = 8 features/lane = 16 B),
// so one load instruction gathers 8 edges (1 KB in flight). 2 loads unrolled =
// 16 edges/iter. Cross-group reduce: shfl_xor 8, 16, 32. deg = end - beg.
// Plain col loads (nontemporal hint measured +15% regression in R11).
__global__ __launch_bounds__(256) void aggregate_bf16_kernel(
    unsigned short* __restrict__ X, const int* __restrict__ row_ptr, const int* __restrict__ col,
    int n_nodes) {
    int lane = threadIdx.x & 63;
    int wid = threadIdx.x >> 6;
    int q = lane >> 3;       // edge slot 0..7
    int j = lane & 7;        // feature oct (features 8j..8j+7)
    int n = blockIdx.x * 4 + wid;
    if (n >= n_nodes) return;
    int beg = row_ptr[n], end = row_ptr[n + 1];
    float a[8] = {0.f, 0.f, 0.f, 0.f, 0.f, 0.f, 0.f, 0.f};
    for (int i = beg; i < end; i += 16) {
        int e0 = i + q, e1 = i + 8 + q;
        bool ok0 = e0 < end, ok1 = e1 < end;
        int s0 = col[ok0 ? e0 : end - 1];
        int s1 = col[ok1 ? e1 : end - 1];
        u32x4 v0 = *reinterpret_cast<const u32x4*>(X + (size_t)s0 * 128 + j * 8);
        u32x4 v1 = *reinterpret_cast<const u32x4*>(X + (size_t)s1 * 128 + j * 8);
        if (ok0) {
#pragma unroll
            for (int k = 0; k < 4; ++k) {
                union { unsigned u; float f; } lo, hi;
                lo.u = v0[k] << 16; hi.u = v0[k] & 0xffff0000u;
                a[2 * k] += lo.f; a[2 * k + 1] += hi.f;
            }
        }
        if (ok1) {
#pragma unroll
            for (int k = 0; k < 4; ++k) {
                union { unsigned u; float f; } lo, hi;
                lo.u = v1[k] << 16; hi.u = v1[k] & 0xffff0000u;
                a[2 * k] += lo.f; a[2 * k + 1] += hi.f;
            }
        }
    }
#pragma unroll
    for (int k = 0; k < 8; ++k) {
        a[k] += __shfl_xor(a[k], 8);
        a[k] += __shfl_xor(a[k], 16);
        a[k] += __shfl_xor(a[k], 32);
    }
    if (q == 0) {
        float dinv = 1.0f / fmaxf((float)(end - beg), 1.0f);
        u32x4 o;
#pragma unroll
        for (int k = 0; k < 4; ++k)
            o[k] = ((unsigned)f2bf(a[2 * k + 1] * dinv) << 16) | f2bf(a[2 * k] * dinv);
        *reinterpret_cast<u32x4*>(X + (size_t)n * 128 + 64 + j * 8) = o;
    }
}

// =================== MFMA linear ===================
__global__ __launch_bounds__(256) void linear_mfma_kernel(
    const unsigned short* __restrict__ X, const unsigned short* __restrict__ WT,
    const float* __restrict__ bias, unsigned short* __restrict__ outBf,
    float* __restrict__ outF32, int n_nodes, int do_relu) {
    int lane = threadIdx.x & 63;
    int wid = threadIdx.x >> 6;
    int l15 = lane & 15;
    int lg = lane >> 4;

    bf16x8 wf[4][4];
#pragma unroll
    for (int ft = 0; ft < 4; ++ft)
#pragma unroll
        for (int ks = 0; ks < 4; ++ks)
            wf[ft][ks] = *reinterpret_cast<const bf16x8*>(
                WT + (size_t)(ft * 16 + l15) * 128 + ks * 32 + lg * 8);

    float4 bv[4];
#pragma unroll
    for (int ft = 0; ft < 4; ++ft)
        bv[ft] = *reinterpret_cast<const float4*>(bias + ft * 16 + lg * 4);

    int tiles = (n_nodes + 15) >> 4;
    for (int tile = blockIdx.x * 4 + wid; tile < tiles; tile += gridDim.x * 4) {
        int nodeBase = tile * 16;
        int nrow = nodeBase + l15;
        int rrow = nrow < n_nodes ? nrow : n_nodes - 1;

        bf16x8 xf[4];
#pragma unroll
        for (int ks = 0; ks < 4; ++ks)
            xf[ks] = *reinterpret_cast<const bf16x8*>(X + (size_t)rrow * 128 + ks * 32 + lg * 8);

        f32x4 acc[4];
#pragma unroll
        for (int ft = 0; ft < 4; ++ft) acc[ft] = (f32x4){0.f, 0.f, 0.f, 0.f};
#pragma unroll
        for (int ks = 0; ks < 4; ++ks) {
#pragma unroll
            for (int ft = 0; ft < 4; ++ft)
                acc[ft] = __builtin_amdgcn_mfma_f32_16x16x32_bf16(wf[ft][ks], xf[ks], acc[ft], 0, 0, 0);
        }

        if (nrow < n_nodes) {
#pragma unroll
            for (int ft = 0; ft < 4; ++ft) {
                float4 v;
                v.x = acc[ft][0] + bv[ft].x;
                v.y = acc[ft][1] + bv[ft].y;
                v.z = acc[ft][2] + bv[ft].z;
                v.w = acc[ft][3] + bv[ft].w;
                if (do_relu) {
                    v.x = fmaxf(v.x, 0.f); v.y = fmaxf(v.y, 0.f);
                    v.z = fmaxf(v.z, 0.f); v.w = fmaxf(v.w, 0.f);
                }
                int fbase = ft * 16 + lg * 4;
                if (outF32) {
                    *reinterpret_cast<float4*>(outF32 + (size_t)nrow * 64 + fbase) = v;
                } else {
                    ushort4 o;
                    o.x = f2bf(v.x); o.y = f2bf(v.y); o.z = f2bf(v.z); o.w = f2bf(v.w);
                    *reinterpret_cast<ushort4*>(outBf + (size_t)nrow * 128 + fbase) = o;
                }
            }
        }
    }
}

// =================== fallback (round-1 atomic scatter, f32) ===================

__global__ void deg_kernel(const int* __restrict__ dst, float* __restrict__ deg, int n_edges) {
    int e = blockIdx.x * blockDim.x + threadIdx.x;
    if (e < n_edges) unsafeAtomicAdd(&deg[dst[e]], 1.0f);
}

__global__ void inv_kernel(float* __restrict__ deg, int n) {
    int i = blockIdx.x * blockDim.x + threadIdx.x;
    if (i < n) deg[i] = 1.0f / fmaxf(deg[i], 1.0f);
}

__global__ __launch_bounds__(256) void scatter_kernel(
    const float* __restrict__ h, const int* __restrict__ src, const int* __restrict__ dst,
    float* __restrict__ agg, int n_edges) {
    int t = blockIdx.x * blockDim.x + threadIdx.x;
    int e = t >> 4;
    if (e >= n_edges) return;
    int q = (t & 15) * 4;
    int s = src[e];
    int d = dst[e];
    float4 v = *reinterpret_cast<const float4*>(h + (size_t)s * NF + q);
    float* o = agg + (size_t)d * NF + q;
    unsafeAtomicAdd(o + 0, v.x);
    unsafeAtomicAdd(o + 1, v.y);
    unsafeAtomicAdd(o + 2, v.z);
    unsafeAtomicAdd(o + 3, v.w);
}

__global__ __launch_bounds__(256) void linear_kernel(
    const float* __restrict__ h, const float* __restrict__ agg, const float* __restrict__ deginv,
    const float* __restrict__ Ws, const float* __restrict__ Wn, const float* __restrict__ bias,
    float* __restrict__ out, int n_nodes, int do_relu) {
    __shared__ float sWs[NF * NF];
    __shared__ float sWn[NF * NF];
    __shared__ float sb[NF];
    for (int i = threadIdx.x; i < NF * NF; i += 256) {
        sWs[i] = Ws[i];
        sWn[i] = Wn[i];
    }
    if (threadIdx.x < NF) sb[threadIdx.x] = bias[threadIdx.x];
    __syncthreads();
    int j = threadIdx.x & 63;
    int sub = threadIdx.x >> 6;
    for (int n = blockIdx.x * 4 + sub; n < n_nodes; n += gridDim.x * 4) {
        const float4* hr = reinterpret_cast<const float4*>(h + (size_t)n * NF);
        const float4* ar = reinterpret_cast<const float4*>(agg + (size_t)n * NF);
        float accS = 0.f, accN = 0.f;
#pragma unroll
        for (int k4 = 0; k4 < 16; ++k4) {
            float4 hv = hr[k4];
            float4 av = ar[k4];
            int kb = k4 * 4;
            accS += hv.x * sWs[(kb + 0) * NF + j];
            accN += av.x * sWn[(kb + 0) * NF + j];
            accS += hv.y * sWs[(kb + 1) * NF + j];
            accN += av.y * sWn[(kb + 1) * NF + j];
            accS += hv.z * sWs[(kb + 2) * NF + j];
            accN += av.z * sWn[(kb + 2) * NF + j];
            accS += hv.w * sWs[(kb + 3) * NF + j];
            accN += av.w * sWn[(kb + 3) * NF + j];
        }
        float val = accS + deginv[n] * accN + sb[j];
        if (do_relu) val = fmaxf(val, 0.f);
        out[(size_t)n * NF + j] = val;
    }
}

// =================== launch ===================

extern "C" void kernel_launch(void* const* d_in, const int* in_sizes, int n_in,
                              void* d_out, int out_size, void* d_ws, size_t ws_size,
                              hipStream_t stream) {
    const float* features = (const float*)d_in[0];
    const int* src = (const int*)d_in[1];
    const int* dst = (const int*)d_in[2];
    const float* Ws0 = (const float*)d_in[3];
    const float* Wn0 = (const float*)d_in[4];
    const float* b0  = (const float*)d_in[5];
    const float* Ws1 = (const float*)d_in[6];
    const float* Wn1 = (const float*)d_in[7];
    const float* b1  = (const float*)d_in[8];
    const float* Ws2 = (const float*)d_in[9];
    const float* Wn2 = (const float*)d_in[10];
    const float* b2  = (const float*)d_in[11];

    const int n_nodes = in_sizes[0] / NF;
    const int n_edges = in_sizes[1];
    float* out = (float*)d_out;

    const int nb = (n_nodes + BUCKET - 1) / BUCKET;
    const size_t alignNB = (((size_t)nb + 1) * 4 + 255) / 256 * 256;
    const size_t alignN = (((size_t)n_nodes + 64) * 4 + 255) / 256 * 256;
    const size_t alignE = ((size_t)n_edges * 4 + 255) / 256 * 256;
    const size_t xBytes = ((size_t)n_nodes * 128 * 2 + 255) / 256 * 256;
    const size_t wtBytes = 3 * 64 * 128 * 2;

    dim3 blk(256);
    const int nEB = (n_edges + EPB - 1) / EPB;
    const int waveBlocks = (n_nodes + 3) / 4;
    const int tiles = (n_nodes + 15) / 16;
    const int linBlocks = (tiles + 3) / 4;
    const int convBlocks = (n_nodes * 16 + 255) / 256;

    // ws layout: bins | bptr | gcur | row_ptr | col | X0 | X1 | WTall
    const size_t need = 3 * alignNB + alignN + alignE + 2 * xBytes + wtBytes;
    const bool outFits = (size_t)out_size * sizeof(float) >= (size_t)n_edges * sizeof(unsigned);

    if (ws_size >= need && nb <= MAXB && n_nodes < (1 << 25) && outFits) {
        char* ws = (char*)d_ws;
        int* bins     = (int*)ws;
        int* bptr     = (int*)(ws + alignNB);
        int* gcur     = (int*)(ws + 2 * alignNB);
        int* row_ptr  = (int*)(ws + 3 * alignNB);
        int* col      = (int*)(ws + 3 * alignNB + alignN);
        unsigned short* X0  = (unsigned short*)(ws + 3 * alignNB + alignN + alignE);
        unsigned short* X1  = (unsigned short*)((char*)X0 + xBytes);
        unsigned short* WT  = (unsigned short*)((char*)X1 + xBytes);
        unsigned short* WT0 = WT;
        unsigned short* WT1 = WT + 64 * 128;
        unsigned short* WT2 = WT + 2 * 64 * 128;
        unsigned* bedges = (unsigned*)d_out;   // dead before final linear writes d_out

        // bucket build
        hipMemsetAsync(bins, 0, (size_t)nb * sizeof(int), stream);
        bhist_kernel<<<nEB, blk, 0, stream>>>(dst, bins, n_edges, nb);
        bscan_kernel<<<1, 1024, 0, stream>>>(bins, bptr, gcur, nb);
        bscatter_kernel<<<nEB, blk, 0, stream>>>(src, dst, gcur, bedges, n_edges, nb);
        bfinal_kernel<<<nb, blk, 0, stream>>>(bedges, bptr, row_ptr, col, n_nodes, n_edges, nb);

        // staging (convert + weight transpose, one dispatch)
        stage_kernel<<<convBlocks + 96, blk, 0, stream>>>(features, X0,
            Ws0, Wn0, Ws1, Wn1, Ws2, Wn2, WT, n_nodes, convBlocks);

        // layer 0: X0 -> X1
        aggregate_bf16_kernel<<<waveBlocks, blk, 0, stream>>>(X0, row_ptr, col, n_nodes);
        linear_mfma_kernel<<<linBlocks, blk, 0, stream>>>(X0, WT0, b0, X1, nullptr, n_nodes, 1);
        // layer 1: X1 -> X0
        aggregate_bf16_kernel<<<waveBlocks, blk, 0, stream>>>(X1, row_ptr, col, n_nodes);
        linear_mfma_kernel<<<linBlocks, blk, 0, stream>>>(X1, WT1, b1, X0, nullptr, n_nodes, 1);
        // layer 2: X0 -> d_out (f32)
        aggregate_bf16_kernel<<<waveBlocks, blk, 0, stream>>>(X0, row_ptr, col, n_nodes);
        linear_mfma_kernel<<<linBlocks, blk, 0, stream>>>(X0, WT2, b2, nullptr, out, n_nodes, 0);
    } else {
        // fallback: atomic-scatter path (f32)
        char* ws = (char*)d_ws;
        size_t degBytes = (((size_t)n_nodes * 4) + 255) / 256 * 256;
        float* deg = (float*)ws;
        float* agg = (float*)(ws + degBytes);
        float* h1  = agg + (size_t)n_nodes * NF;
        int scatBlocks = (n_edges * 16 + 255) / 256;
        int eBlocks = (n_edges + 255) / 256;
        int waveBlocksF = (n_nodes + 3) / 4;
        size_t rowBytes = (size_t)n_nodes * NF * sizeof(float);

        hipMemsetAsync(deg, 0, (size_t)n_nodes * sizeof(float), stream);
        deg_kernel<<<eBlocks, blk, 0, stream>>>(dst, deg, n_edges);
        inv_kernel<<<(n_nodes + 255) / 256, blk, 0, stream>>>(deg, n_nodes);

        hipMemsetAsync(agg, 0, rowBytes, stream);
        scatter_kernel<<<scatBlocks, blk, 0, stream>>>(features, src, dst, agg, n_edges);
        linear_kernel<<<waveBlocksF, blk, 0, stream>>>(features, agg, deg, Ws0, Wn0, b0, out, n_nodes, 1);

        hipMemsetAsync(agg, 0, rowBytes, stream);
        scatter_kernel<<<scatBlocks, blk, 0, stream>>>(out, src, dst, agg, n_edges);
        linear_kernel<<<waveBlocksF, blk, 0, stream>>>(out, agg, deg, Ws1, Wn1, b1, h1, n_nodes, 1);

        hipMemsetAsync(agg, 0, rowBytes, stream);
        scatter_kernel<<<scatBlocks, blk, 0, stream>>>(h1, src, dst, agg, n_edges);
        linear_kernel<<<waveBlocksF, blk, 0, stream>>>(h1, agg, deg, Ws2, Wn2, b2, out, n_nodes, 0);
    }
}